// Round 9
// baseline (69.141 us; speedup 1.0000x reference)
//
#include <hip/hip_runtime.h>

#define BB 8
#define CC 128
#define HH 64
#define WW 64
#define OO 128
#define KT 9
#define HWs (HH * WW)

typedef __attribute__((ext_vector_type(8))) _Float16 half8;
typedef __attribute__((ext_vector_type(8))) short short8;
typedef __attribute__((ext_vector_type(4))) float f32x4;

__device__ inline unsigned short f2bf(float f) {
    union { float f; unsigned int u; } x; x.f = f;
    unsigned int u = x.u;
    unsigned int r = u + 0x7fff + ((u >> 16) & 1);
    return (unsigned short)(r >> 16);
}

// ---- prep 1: NCHW f32 -> NHWC f16 (proven) ----
__global__ __launch_bounds__(256) void prep_input(
    const float* __restrict__ in, _Float16* __restrict__ out) {
    __shared__ float t[CC][33];
    int b = blockIdx.y;
    int s0 = blockIdx.x * 32;
    int s = threadIdx.x & 31;
    int c0 = threadIdx.x >> 5;
    const float* ip = in + (size_t)b * CC * HWs;
#pragma unroll
    for (int c = 0; c < CC; c += 8)
        t[c + c0][s] = ip[(size_t)(c + c0) * HWs + s0 + s];
    __syncthreads();
    int ws = threadIdx.x >> 3;
    int cg = (threadIdx.x & 7) * 16;
    _Float16 v[16];
#pragma unroll
    for (int i = 0; i < 16; ++i) v[i] = (_Float16)t[cg + i][ws];
    _Float16* op = out + ((size_t)(b * HWs) + s0 + ws) * CC + cg;
    *(half8*)op = *(half8*)&v[0];
    *(half8*)(op + 8) = *(half8*)&v[8];
}

// ---- prep 2 (proven): weight (O,C,3,3) f32 -> wbf[k][o][c] bf16 ----
__global__ __launch_bounds__(256) void prep_weight(
    const float* __restrict__ w, unsigned short* __restrict__ wbf) {
    int i = blockIdx.x * 256 + threadIdx.x;
    if (i >= KT * OO * CC) return;
    int k = i / (OO * CC);
    int r = i % (OO * CC);
    int o = r >> 7, c = r & 127;
    wbf[i] = f2bf(w[o * (CC * KT) + c * KT + k]);
}

// ---- main ----
struct GatherR {
    half8 g[8];                 // [corner][cc]: 4 corners x 2 chunks of 8 ch
    float w00, w01, w10, w11;
};

__device__ __forceinline__ void sample_issue(
    const _Float16* __restrict__ base, int ho, int wo, int cs, int k,
    float oy, float ox, float mm, GatherR& G) {
    int kh = k / 3, kw = k % 3;
    float py = (float)(ho - 1 + kh) + oy;
    float px = (float)(wo - 1 + kw) + ox;
    float fy = floorf(py), fx = floorf(px);
    float wy1 = py - fy, wx1 = px - fx;
    float wy0 = 1.f - wy1, wx0 = 1.f - wx1;
    int y0 = (int)fy, x0 = (int)fx;
    int y1 = y0 + 1, x1 = x0 + 1;
    bool vy0 = (y0 >= 0) & (y0 < HH);
    bool vy1 = (y1 >= 0) & (y1 < HH);
    bool vx0 = (x0 >= 0) & (x0 < WW);
    bool vx1 = (x1 >= 0) & (x1 < WW);
    G.w00 = (vy0 & vx0) ? wy0 * wx0 * mm : 0.f;
    G.w01 = (vy0 & vx1) ? wy0 * wx1 * mm : 0.f;
    G.w10 = (vy1 & vx0) ? wy1 * wx0 * mm : 0.f;
    G.w11 = (vy1 & vx1) ? wy1 * wx1 * mm : 0.f;
    int y0c = min(max(y0, 0), HH - 1), y1c = min(max(y1, 0), HH - 1);
    int x0c = min(max(x0, 0), WW - 1), x1c = min(max(x1, 0), WW - 1);
    const _Float16* p00 = base + (size_t)(y0c * WW + x0c) * CC + cs;
    const _Float16* p01 = base + (size_t)(y0c * WW + x1c) * CC + cs;
    const _Float16* p10 = base + (size_t)(y1c * WW + x0c) * CC + cs;
    const _Float16* p11 = base + (size_t)(y1c * WW + x1c) * CC + cs;
    G.g[0] = *(const half8*)p00;  G.g[1] = *(const half8*)(p00 + 32);
    G.g[2] = *(const half8*)p01;  G.g[3] = *(const half8*)(p01 + 32);
    G.g[4] = *(const half8*)p10;  G.g[5] = *(const half8*)(p10 + 32);
    G.g[6] = *(const half8*)p11;  G.g[7] = *(const half8*)(p11 + 32);
}

__global__ __launch_bounds__(512, 4) void deform_main(
    const _Float16* __restrict__ inh, const unsigned short* __restrict__ wbf,
    const float* __restrict__ offset, const float* __restrict__ mask,
    const float* __restrict__ bias, float* __restrict__ out) {
    __shared__ unsigned short Bl[2][OO * CC];  // 2 x 32 KB

    // 512 blocks; XCD x owns batch image b = x (2 MB f16 in its 4 MB L2)
    int hw = blockIdx.x;
    int lb = (hw & 7) * 64 + (hw >> 3);
    int ho = lb & 63;
    int b = lb >> 6;

    int tid = threadIdx.x;
    int wv = tid >> 6, l = tid & 63;
    int lr = l & 15, lg = l >> 4;
    int p = wv >> 1;               // pixel quarter (0..3)
    int khalf = wv & 1;            // channel half (0..1)
    int wo = p * 16 + lr;          // this lane's pixel
    int cs = khalf * 64 + lg * 8;  // first channel chunk (second is +32)

    // B staging role: each thread 64 B of one row
    int o_s = tid >> 2;
    int cbyte = (tid & 3) * 64;

    const _Float16* base = inh + (size_t)b * HWs * CC;
    const float* offp = offset + (size_t)b * 18 * HWs + ho * WW + wo;
    const float* mskp = mask + (size_t)b * 9 * HWs + ho * WW + wo;

    f32x4 acc[8] = {};
    GatherR G0, G1;
    int4 breg[4];

    // ---- prologue: B(0); gathers(0)->G0; gathers(1)->G1; offs(2) ----
    {
        const int4* src = (const int4*)((const char*)wbf + (size_t)o_s * 256 + cbyte);
#pragma unroll
        for (int j = 0; j < 4; ++j) breg[j] = src[j];
    }
    {
        float oy = offp[0], ox = offp[HWs], mm = mskp[0];
        sample_issue(base, ho, wo, cs, 0, oy, ox, mm, G0);
    }
    float oyN = offp[2 * HWs], oxN = offp[3 * HWs], mmN = mskp[HWs];
    sample_issue(base, ho, wo, cs, 1, oyN, oxN, mmN, G1);
    oyN = offp[4 * HWs]; oxN = offp[5 * HWs]; mmN = mskp[2 * HWs];
    {
        char* dst = (char*)Bl[0] + o_s * 256;
#pragma unroll
        for (int j = 0; j < 4; ++j)
            *(int4*)(dst + ((cbyte + j * 16) ^ ((o_s & 15) << 4))) = breg[j];
    }
    __syncthreads();

#pragma unroll
    for (int k = 0; k < KT; ++k) {
        // (0) issue B(k+1) loads first (oldest in queue -> its later write
        //     wait never drains the gathers)
        if (k < KT - 1) {
            const int4* src = (const int4*)((const char*)wbf +
                              (size_t)(k + 1) * OO * CC * 2 + (size_t)o_s * 256 + cbyte);
#pragma unroll
            for (int j = 0; j < 4; ++j) breg[j] = src[j];
        }

        // (1) interp tap k from G[k&1] (issued two taps ago)
        GatherR& Gc = (k & 1) ? G1 : G0;
        short8 af[2];
#pragma unroll
        for (int cc = 0; cc < 2; ++cc)
#pragma unroll
            for (int j = 0; j < 8; ++j) {
                float s = Gc.w00 * (float)Gc.g[0 * 2 + cc][j] +
                          Gc.w01 * (float)Gc.g[1 * 2 + cc][j] +
                          Gc.w10 * (float)Gc.g[2 * 2 + cc][j] +
                          Gc.w11 * (float)Gc.g[3 * 2 + cc][j];
                af[cc][j] = (short)f2bf(s);
            }

        // (2) refill G[k&1] with gathers(k+2); prefetch offsets(k+3)
        if (k < KT - 2) {
            sample_issue(base, ho, wo, cs, k + 2, oyN, oxN, mmN, Gc);
            if (k < KT - 3) {
                oyN = offp[(2 * k + 6) * HWs];
                oxN = offp[(2 * k + 7) * HWs];
                mmN = mskp[(k + 3) * HWs];
            }
        }

        // (3) MFMA tap k: A regs, B from Bl[k&1]
#pragma unroll
        for (int cc = 0; cc < 2; ++cc) {
            unsigned colb = (unsigned)((khalf * 2 + cc) * 64 + lg * 16);
#pragma unroll
            for (int n = 0; n < 8; ++n) {
                int o = n * 16 + lr;
                unsigned baddr = (unsigned)(o * 256 + (colb ^ (lr << 4)));
                short8 bf = *(const short8*)((const char*)Bl[k & 1] + baddr);
                acc[n] = __builtin_amdgcn_mfma_f32_16x16x32_bf16(
                    af[cc], bf, acc[n], 0, 0, 0);
            }
        }

        // (4) write B(k+1); single barrier per tap
        if (k < KT - 1) {
            char* dst = (char*)Bl[(k + 1) & 1] + o_s * 256;
#pragma unroll
            for (int j = 0; j < 4; ++j)
                *(int4*)(dst + ((cbyte + j * 16) ^ ((o_s & 15) << 4))) = breg[j];
            __syncthreads();
        }
    }

    // ---- K-split pair reduction via Bl[1] (last tap k=8 read Bl[0]) ----
    float* L = (float*)&Bl[1][0];  // 4 quarters x 16 px x 128 o = 32 KB
    if (khalf) {
#pragma unroll
        for (int n = 0; n < 8; ++n)
#pragma unroll
            for (int j = 0; j < 4; ++j)
                L[(size_t)(p * 16 + lg * 4 + j) * 128 + n * 16 + lr] = acc[n][j];
    }
    __syncthreads();
    if (!khalf) {
#pragma unroll
        for (int n = 0; n < 8; ++n) {
            int o = n * 16 + lr;
            float bs = bias[o];
            float4 v;
            v.x = acc[n][0] + bs + L[(size_t)(p * 16 + lg * 4 + 0) * 128 + o];
            v.y = acc[n][1] + bs + L[(size_t)(p * 16 + lg * 4 + 1) * 128 + o];
            v.z = acc[n][2] + bs + L[(size_t)(p * 16 + lg * 4 + 2) * 128 + o];
            v.w = acc[n][3] + bs + L[(size_t)(p * 16 + lg * 4 + 3) * 128 + o];
            int wo0 = p * 16 + lg * 4;
            *(float4*)(out + (size_t)(b * OO + o) * HWs + ho * WW + wo0) = v;
        }
    }
}

extern "C" void kernel_launch(void* const* d_in, const int* in_sizes, int n_in,
                              void* d_out, int out_size, void* d_ws, size_t ws_size,
                              hipStream_t stream) {
    const float* inp    = (const float*)d_in[0];
    const float* offset = (const float*)d_in[1];
    const float* mask   = (const float*)d_in[2];
    const float* weight = (const float*)d_in[3];
    const float* bias   = (const float*)d_in[4];
    float* out = (float*)d_out;

    _Float16* inh = (_Float16*)d_ws;  // 8 MB
    unsigned short* wbf =
        (unsigned short*)((char*)d_ws + (size_t)BB * HWs * CC * sizeof(_Float16));

    prep_input<<<dim3(128, 8), 256, 0, stream>>>(inp, inh);
    prep_weight<<<dim3((KT * OO * CC + 255) / 256), 256, 0, stream>>>(weight, wbf);
    deform_main<<<dim3(512), 512, 0, stream>>>(inh, wbf, offset, mask, bias, out);
}